// Round 15
// baseline (116.751 us; speedup 1.0000x reference)
//
#include <hip/hip_runtime.h>
#include <stdint.h>

#define CW 48
#define HR 3
#define VR 3
#define BB 2
#define CC 16
#define HH 128
#define WW 256

#define LW 312      // Lsh stride: idx = x+3; max read idx 308
#define RW2 264     // Rsh stride: idx = x+3, valid data 3..258
#define SW 264      // Ssh stride: xi 0..261 used
#define FWD (WW*CW) // 12288 elements per (b,h) plane
#define HSEG 8
#define REPS_A 10
#define REPS_B 8

__device__ __forceinline__ uint32_t bf16rn(float f) {
    uint32_t x = __builtin_bit_cast(uint32_t, f);
    uint32_t lsb = (x >> 16) & 1u;
    x += 0x7fffu + lsb;
    return x >> 16;
}
__device__ __forceinline__ float bflo(uint32_t u) {
    return __builtin_bit_cast(float, u << 16);
}
__device__ __forceinline__ float bfhi(uint32_t u) {
    return __builtin_bit_cast(float, u & 0xffff0000u);
}

// ------- Kernel A (r8 exact, x REPS_A): one block per (b,y); 512 threads -------
// MEASUREMENT build: body repeated REPS_A times (idempotent — all LDS/global
// writes rewrite identical values). `zero`==0 defeats load hoisting across reps.
__global__ __launch_bounds__(512) void ssd_hraw_rep(
    const float* __restrict__ Lg, const float* __restrict__ Rg,
    uint16_t* __restrict__ Hws, int zero)
{
    const int bid = blockIdx.x;     // 0..255
    const int y   = bid % HH;
    const int b   = bid / HH;
    const int tid = threadIdx.x;

    __shared__ float Lsh[CC * LW];
    __shared__ float Rsh[CC * RW2];
    __shared__ float Ssh[CW * SW];
    __shared__ float el[LW];
    __shared__ float er[RW2];

    const int chalf = tid >> 8;            // 0: c 0..7, 1: c 8..15
    const int unit  = tid & 255;
    const int q     = unit >> 6;           // d0 = 12q
    const int xi0   = (unit & 63) * 4;     // 0..252
    const int d0    = q * 12;

    for (int rep = 0; rep < REPS_A; ++rep) {
        // ---- zero pad regions ----
        for (int i = tid; i < CC * 56; i += 512) {      // Lsh idx 0..2, 259..311
            int c = i / 56, j = i % 56;
            int idx = (j < 3) ? j : (256 + j);
            Lsh[c * LW + idx] = 0.f;
        }
        for (int i = tid; i < CC * 8; i += 512) {       // Rsh idx 0..2, 259..263
            int c = i >> 3, j = i & 7;
            int idx = (j < 3) ? j : (256 + j);
            Rsh[c * RW2 + idx] = 0.f;
        }
        if (tid < 56) { int idx = (tid < 3) ? tid : (256 + tid); el[idx] = 0.f; }
        else if (tid < 64) { int j = tid - 56; int idx = (j < 3) ? j : (256 + j); er[idx] = 0.f; }

        // ---- stage: waves 0-3 load L, waves 4-7 load R; el/er in regs ----
        {
            const int img = tid >> 8;
            const int col = tid & 255;
            const float* __restrict__ base =
                (img ? Rg : Lg) + ((size_t)b * CC) * (HH * WW)
                + (size_t)(y + zero * rep) * WW + col;
            float* sh = (img ? &Rsh[HR + col] : &Lsh[HR + col]);
            const int stride = img ? RW2 : LW;
            float e = 0.f;
            #pragma unroll
            for (int c = 0; c < CC; ++c) {
                float v = base[(size_t)c * (HH * WW)];
                sh[c * stride] = v;
                e = fmaf(v, v, e);
            }
            (img ? er : el)[HR + col] = e;
        }
        __syncthreads();

        // ---- cc partials: 8 channels for this thread's (q, xi0) unit ----
        float acc[12][4];
        #pragma unroll
        for (int dd = 0; dd < 12; ++dd)
            #pragma unroll
            for (int xv = 0; xv < 4; ++xv) acc[dd][xv] = 0.f;

        {
            const int c0 = chalf * 8;
            #pragma unroll
            for (int ci = 0; ci < 8; ++ci) {
                const int c = c0 + ci;
                const float4 rv = *(const float4*)&Rsh[c * RW2 + xi0];
                const float rr[4] = {rv.x, rv.y, rv.z, rv.w};
                float lv[16];
                #pragma unroll
                for (int k = 0; k < 4; ++k)
                    *(float4*)&lv[4 * k] = *(const float4*)&Lsh[c * LW + xi0 + d0 + 4 * k];
                #pragma unroll
                for (int dd = 0; dd < 12; ++dd)
                    #pragma unroll
                    for (int xv = 0; xv < 4; ++xv)
                        acc[dd][xv] = fmaf(lv[dd + xv], rr[xv], acc[dd][xv]);
            }
        }

        if (chalf == 0) {
            float elv[16];
            #pragma unroll
            for (int k = 0; k < 4; ++k)
                *(float4*)&elv[4 * k] = *(const float4*)&el[xi0 + d0 + 4 * k];
            const float4 e4 = *(const float4*)&er[xi0];
            const float err4[4] = {e4.x, e4.y, e4.z, e4.w};
            #pragma unroll
            for (int dd = 0; dd < 12; ++dd) {
                float4 o;
                o.x = elv[dd + 0] + err4[0] - 2.f * acc[dd][0];
                o.y = elv[dd + 1] + err4[1] - 2.f * acc[dd][1];
                o.z = elv[dd + 2] + err4[2] - 2.f * acc[dd][2];
                o.w = elv[dd + 3] + err4[3] - 2.f * acc[dd][3];
                *(float4*)&Ssh[(d0 + dd) * SW + xi0] = o;
            }
        } else {
            for (int p = tid - 256; p < 6 * CW; p += 256) {
                int dd = p % CW;
                int xi = 256 + p / CW;
                float a = 0.f;
                #pragma unroll
                for (int c = 0; c < CC; ++c)
                    a = fmaf(Lsh[c * LW + xi + dd], Rsh[c * RW2 + xi], a);
                Ssh[dd * SW + xi] = el[xi + dd] + er[xi] - 2.f * a;
            }
        }
        __syncthreads();

        if (chalf == 1) {
            #pragma unroll
            for (int dd = 0; dd < 12; ++dd) {
                float4 v = *(const float4*)&Ssh[(d0 + dd) * SW + xi0];
                v.x = fmaf(-2.f, acc[dd][0], v.x);
                v.y = fmaf(-2.f, acc[dd][1], v.y);
                v.z = fmaf(-2.f, acc[dd][2], v.z);
                v.w = fmaf(-2.f, acc[dd][3], v.w);
                *(float4*)&Ssh[(d0 + dd) * SW + xi0] = v;
            }
        }
        __syncthreads();

        // ---- horizontal 7-tap, bf16 store ----
        {
            const int j   = tid & 127;
            const int qh  = tid >> 7;
            const int w0  = 2 * j;
            const int dh0 = qh * 12;
            float hs[12][2];
            #pragma unroll
            for (int dd = 0; dd < 12; ++dd) {
                const float* row = &Ssh[(dh0 + dd) * SW];
                const float4 a  = *(const float4*)&row[w0];
                const float4 bv = *(const float4*)&row[w0 + 4];
                float h0 = a.x + a.y + a.z + a.w + bv.x + bv.y + bv.z;
                hs[dd][0] = h0;
                hs[dd][1] = h0 - a.x + bv.w;
            }
            uint16_t* H = Hws + (size_t)(b * HH + y) * FWD;
            #pragma unroll
            for (int xv = 0; xv < 2; ++xv) {
                uint32_t pk[6];
                #pragma unroll
                for (int i = 0; i < 6; ++i)
                    pk[i] = bf16rn(hs[2 * i][xv]) | (bf16rn(hs[2 * i + 1][xv]) << 16);
                uint32_t* p = (uint32_t*)(H + (size_t)(w0 + xv) * CW + dh0);
                *(uint2*)&p[0] = make_uint2(pk[0], pk[1]);
                *(uint2*)&p[2] = make_uint2(pk[2], pk[3]);
                *(uint2*)&p[4] = make_uint2(pk[4], pk[5]);
            }
        }
        __syncthreads();   // clean rep separation
    }
}

// ------- Kernel B (r8 exact, x REPS_B): vertical 7-tap over bf16 Hws -------
__global__ __launch_bounds__(256) void vbox_rep(
    const uint16_t* __restrict__ Hws, float* __restrict__ out, int zero)
{
    const int bid = blockIdx.x;               // grid: BB * (HH/HSEG) * 24
    const int g   = bid % 24;
    const int hs  = (bid / 24) % (HH / HSEG);
    const int b   = bid / (24 * (HH / HSEG));
    const int f2  = g * 256 + threadIdx.x;    // short2-column, 0..6143
    const int h0  = hs * HSEG;

    const uint16_t* H = Hws + (size_t)b * HH * FWD + 2 * f2;
    float*          O = out + (size_t)b * HH * FWD + 2 * f2;

    for (int rep = 0; rep < REPS_B; ++rep) {
        const size_t roff = (size_t)(zero * rep) * FWD;   // == 0, defeats hoisting
        float vlo[HSEG + 6], vhi[HSEG + 6];
        if (h0 >= 3 && h0 + HSEG + 2 < HH) {
            #pragma unroll
            for (int k = 0; k < HSEG + 6; ++k) {
                uint32_t u = *(const uint32_t*)&H[(size_t)(h0 - 3 + k) * FWD + roff];
                vlo[k] = bflo(u);
                vhi[k] = bfhi(u);
            }
        } else {
            #pragma unroll
            for (int k = 0; k < HSEG + 6; ++k) {
                int yy = h0 - 3 + k;
                if (yy >= 0 && yy < HH) {
                    uint32_t u = *(const uint32_t*)&H[(size_t)yy * FWD + roff];
                    vlo[k] = bflo(u);
                    vhi[k] = bfhi(u);
                } else { vlo[k] = 0.f; vhi[k] = 0.f; }
            }
        }
        #pragma unroll
        for (int hi = 0; hi < HSEG; ++hi) {
            float slo = vlo[hi], shi = vhi[hi];
            #pragma unroll
            for (int k = 1; k < 7; ++k) { slo += vlo[hi + k]; shi += vhi[hi + k]; }
            *(float2*)&O[(size_t)(h0 + hi) * FWD] = make_float2(slo, shi);
        }
    }
}

extern "C" void kernel_launch(void* const* d_in, const int* in_sizes, int n_in,
                              void* d_out, int out_size, void* d_ws, size_t ws_size,
                              hipStream_t stream) {
    const float* L = (const float*)d_in[0];
    const float* R = (const float*)d_in[1];
    float* outp = (float*)d_out;
    uint16_t* Hws = (uint16_t*)d_ws;   // BB*HH*WW*CW*2 = 6.3 MB

    // MEASUREMENT ROUND: r8-exact kernels with in-kernel repeats so both
    // surface in the rocprof top-5 with counters (fills are ~40us each).
    ssd_hraw_rep<<<dim3(BB * HH), 512, 0, stream>>>(L, R, Hws, 0);
    vbox_rep<<<dim3(BB * (HH / HSEG) * 24), 256, 0, stream>>>(Hws, outp, 0);
}

// Round 16
// 24.037 us; speedup vs baseline: 4.8572x; 4.8572x over previous
//
#include <hip/hip_runtime.h>
#include <hip/hip_fp16.h>
#include <stdint.h>

#define CW 48
#define HR 3
#define VR 3
#define BB 2
#define CC 16
#define HH 128
#define WW 256

#define LW 312      // Lsh stride (u32 f16x2 units): idx = x+3; max read idx 308
#define RW2 264     // Rsh stride: idx = x+3, valid data 3..258
#define SW 264      // Ssh stride (fp32): xi 0..261 used
#define FWD (WW*CW) // 12288 elements per (b,h) plane
#define HSEG 8

__device__ __forceinline__ uint32_t bf16rn(float f) {
    uint32_t x = __builtin_bit_cast(uint32_t, f);
    uint32_t lsb = (x >> 16) & 1u;
    x += 0x7fffu + lsb;
    return x >> 16;
}
__device__ __forceinline__ float bflo(uint32_t u) {
    return __builtin_bit_cast(float, u << 16);
}
__device__ __forceinline__ float bfhi(uint32_t u) {
    return __builtin_bit_cast(float, u & 0xffff0000u);
}

// f16x2 dot with f32 accumulate: acc += a.x*b.x + a.y*b.y  (v_dot2_f32_f16)
__device__ __forceinline__ float fdot2f(uint32_t a, uint32_t b, float c) {
#if defined(__has_builtin) && __has_builtin(__builtin_amdgcn_fdot2)
    typedef _Float16 h2 __attribute__((ext_vector_type(2)));
    return __builtin_amdgcn_fdot2(__builtin_bit_cast(h2, a),
                                  __builtin_bit_cast(h2, b), c, false);
#else
    float2 fa = __half22float2(__builtin_bit_cast(__half2, a));
    float2 fb = __half22float2(__builtin_bit_cast(__half2, b));
    return fmaf(fa.y, fb.y, fmaf(fa.x, fb.x, c));
#endif
}

// ------------- Kernel A: one block per (b,y) row; 512 threads -------------
// L/R staged as f16x2 channel-pairs; cc via v_dot2; ssd = el+er-2cc (el/er fp32)
// Hws[b][y][w][d] (bf16) = horizontal 7-tap of ssd_raw(y, x, d)
__global__ __launch_bounds__(512) void ssd_hraw(
    const float* __restrict__ Lg, const float* __restrict__ Rg,
    uint16_t* __restrict__ Hws)
{
    const int bid = blockIdx.x;     // 0..255
    const int y   = bid % HH;
    const int b   = bid / HH;
    const int tid = threadIdx.x;

    __shared__ uint32_t Lsh[8 * LW];     // 10.0 KB (f16x2 channel-pairs)
    __shared__ uint32_t Rsh[8 * RW2];    //  8.4 KB
    __shared__ float    Ssh[CW * SW];    // 49.5 KB
    __shared__ float    el[LW];          //  1.2 KB
    __shared__ float    er[RW2];         //  1.1 KB   -> ~70.3 KB total

    // ---- zero pad regions (valid cols overwritten below) ----
    for (int i = tid; i < 8 * 56; i += 512) {       // Lsh idx 0..2, 259..311
        int ci = i / 56, j = i % 56;
        int idx = (j < 3) ? j : (256 + j);
        Lsh[ci * LW + idx] = 0u;
    }
    for (int i = tid; i < 8 * 8; i += 512) {        // Rsh idx 0..2, 259..263
        int ci = i >> 3, j = i & 7;
        int idx = (j < 3) ? j : (256 + j);
        Rsh[ci * RW2 + idx] = 0u;
    }
    if (tid < 56) { int idx = (tid < 3) ? tid : (256 + tid); el[idx] = 0.f; }
    else if (tid < 64) { int j = tid - 56; int idx = (j < 3) ? j : (256 + j); er[idx] = 0.f; }

    // ---- stage: waves 0-3 load L column, waves 4-7 load R column ----
    // loads fp32 (el/er exact), packs channel-pairs to f16x2 for LDS
    {
        const int img = tid >> 8;          // 0 = L, 1 = R
        const int col = tid & 255;
        const size_t plane = (size_t)HH * WW;
        const float* __restrict__ base =
            (img ? Rg : Lg) + (size_t)b * CC * plane + (size_t)y * WW + col;
        uint32_t* sh = (img ? &Rsh[HR + col] : &Lsh[HR + col]);
        const int stride = img ? RW2 : LW;
        float e = 0.f;
        #pragma unroll
        for (int ci = 0; ci < 8; ++ci) {
            float v0 = base[(size_t)(2 * ci)     * plane];
            float v1 = base[(size_t)(2 * ci + 1) * plane];
            e = fmaf(v0, v0, e);
            e = fmaf(v1, v1, e);
            __half2 h = __floats2half2_rn(v0, v1);
            sh[ci * stride] = __builtin_bit_cast(uint32_t, h);
        }
        (img ? er : el)[HR + col] = e;
    }
    __syncthreads();

    // ---- cc partials: each thread does 4 channel-PAIRS (8 ch) for its unit ----
    const int chalf = tid >> 8;            // 0: cpairs 0..3, 1: cpairs 4..7
    const int unit  = tid & 255;
    const int q     = unit >> 6;           // d0 = 12q
    const int xi0   = (unit & 63) * 4;     // 0..252
    const int d0    = q * 12;

    float acc[12][4];
    #pragma unroll
    for (int dd = 0; dd < 12; ++dd)
        #pragma unroll
        for (int xv = 0; xv < 4; ++xv) acc[dd][xv] = 0.f;

    {
        const int c0 = chalf * 4;
        #pragma unroll
        for (int ci = 0; ci < 4; ++ci) {
            const int c = c0 + ci;
            const uint4 rv = *(const uint4*)&Rsh[c * RW2 + xi0];   // 4 xi f16x2
            const uint32_t rr[4] = {rv.x, rv.y, rv.z, rv.w};
            uint32_t lv[16];
            #pragma unroll
            for (int k = 0; k < 4; ++k)
                *(uint4*)&lv[4 * k] = *(const uint4*)&Lsh[c * LW + xi0 + d0 + 4 * k];
            #pragma unroll
            for (int dd = 0; dd < 12; ++dd)
                #pragma unroll
                for (int xv = 0; xv < 4; ++xv)
                    acc[dd][xv] = fdot2f(lv[dd + xv], rr[xv], acc[dd][xv]);
        }
    }

    if (chalf == 0) {
        float elv[16];
        #pragma unroll
        for (int k = 0; k < 4; ++k)
            *(float4*)&elv[4 * k] = *(const float4*)&el[xi0 + d0 + 4 * k];
        const float4 e4 = *(const float4*)&er[xi0];
        const float err4[4] = {e4.x, e4.y, e4.z, e4.w};
        #pragma unroll
        for (int dd = 0; dd < 12; ++dd) {
            float4 o;
            o.x = elv[dd + 0] + err4[0] - 2.f * acc[dd][0];
            o.y = elv[dd + 1] + err4[1] - 2.f * acc[dd][1];
            o.z = elv[dd + 2] + err4[2] - 2.f * acc[dd][2];
            o.w = elv[dd + 3] + err4[3] - 2.f * acc[dd][3];
            *(float4*)&Ssh[(d0 + dd) * SW + xi0] = o;
        }
    } else {
        // leftover xi 256..261 (288 values), all 8 cpairs, final value
        for (int p = tid - 256; p < 6 * CW; p += 256) {
            int dd = p % CW;
            int xi = 256 + p / CW;
            float a = 0.f;
            #pragma unroll
            for (int ci = 0; ci < 8; ++ci)
                a = fdot2f(Lsh[ci * LW + xi + dd], Rsh[ci * RW2 + xi], a);
            Ssh[dd * SW + xi] = el[xi + dd] + er[xi] - 2.f * a;
        }
    }
    __syncthreads();

    if (chalf == 1) {
        // merge second channel-half: Ssh -= 2*acc
        #pragma unroll
        for (int dd = 0; dd < 12; ++dd) {
            float4 v = *(const float4*)&Ssh[(d0 + dd) * SW + xi0];
            v.x = fmaf(-2.f, acc[dd][0], v.x);
            v.y = fmaf(-2.f, acc[dd][1], v.y);
            v.z = fmaf(-2.f, acc[dd][2], v.z);
            v.w = fmaf(-2.f, acc[dd][3], v.w);
            *(float4*)&Ssh[(d0 + dd) * SW + xi0] = v;
        }
    }
    __syncthreads();

    // ---- horizontal 7-tap, 512 threads: (qh = d-quarter, 2 w per thread), bf16 store ----
    {
        const int j   = tid & 127;         // w0 = 2j
        const int qh  = tid >> 7;
        const int w0  = 2 * j;
        const int dh0 = qh * 12;
        float hs[12][2];
        #pragma unroll
        for (int dd = 0; dd < 12; ++dd) {
            const float* row = &Ssh[(dh0 + dd) * SW];
            const float4 a  = *(const float4*)&row[w0];
            const float4 bv = *(const float4*)&row[w0 + 4];
            float h0 = a.x + a.y + a.z + a.w + bv.x + bv.y + bv.z;
            hs[dd][0] = h0;
            hs[dd][1] = h0 - a.x + bv.w;
        }
        uint16_t* H = Hws + (size_t)(b * HH + y) * FWD;
        #pragma unroll
        for (int xv = 0; xv < 2; ++xv) {
            uint32_t pk[6];
            #pragma unroll
            for (int i = 0; i < 6; ++i)
                pk[i] = bf16rn(hs[2 * i][xv]) | (bf16rn(hs[2 * i + 1][xv]) << 16);
            uint32_t* p = (uint32_t*)(H + (size_t)(w0 + xv) * CW + dh0);  // 8B-aligned
            *(uint2*)&p[0] = make_uint2(pk[0], pk[1]);
            *(uint2*)&p[2] = make_uint2(pk[2], pk[3]);
            *(uint2*)&p[4] = make_uint2(pk[4], pk[5]);
        }
    }
}

// ------------- Kernel B (r8 exact): vertical 7-tap over bf16 Hws, fp32 out -------------
__global__ __launch_bounds__(256) void vbox(
    const uint16_t* __restrict__ Hws, float* __restrict__ out)
{
    const int bid = blockIdx.x;               // grid: BB * (HH/HSEG) * 24
    const int g   = bid % 24;
    const int hs  = (bid / 24) % (HH / HSEG);
    const int b   = bid / (24 * (HH / HSEG));
    const int f2  = g * 256 + threadIdx.x;    // short2-column, 0..6143
    const int h0  = hs * HSEG;

    const uint16_t* H = Hws + (size_t)b * HH * FWD + 2 * f2;
    float*          O = out + (size_t)b * HH * FWD + 2 * f2;

    float vlo[HSEG + 6], vhi[HSEG + 6];
    if (h0 >= 3 && h0 + HSEG + 2 < HH) {
        #pragma unroll
        for (int k = 0; k < HSEG + 6; ++k) {
            uint32_t u = *(const uint32_t*)&H[(size_t)(h0 - 3 + k) * FWD];
            vlo[k] = bflo(u);
            vhi[k] = bfhi(u);
        }
    } else {
        #pragma unroll
        for (int k = 0; k < HSEG + 6; ++k) {
            int yy = h0 - 3 + k;
            if (yy >= 0 && yy < HH) {
                uint32_t u = *(const uint32_t*)&H[(size_t)yy * FWD];
                vlo[k] = bflo(u);
                vhi[k] = bfhi(u);
            } else { vlo[k] = 0.f; vhi[k] = 0.f; }
        }
    }
    #pragma unroll
    for (int hi = 0; hi < HSEG; ++hi) {
        float slo = vlo[hi], shi = vhi[hi];
        #pragma unroll
        for (int k = 1; k < 7; ++k) { slo += vlo[hi + k]; shi += vhi[hi + k]; }
        *(float2*)&O[(size_t)(h0 + hi) * FWD] = make_float2(slo, shi);
    }
}

extern "C" void kernel_launch(void* const* d_in, const int* in_sizes, int n_in,
                              void* d_out, int out_size, void* d_ws, size_t ws_size,
                              hipStream_t stream) {
    const float* L = (const float*)d_in[0];
    const float* R = (const float*)d_in[1];
    float* outp = (float*)d_out;
    uint16_t* Hws = (uint16_t*)d_ws;   // BB*HH*WW*CW*2 = 6.3 MB

    ssd_hraw<<<dim3(BB * HH), 512, 0, stream>>>(L, R, Hws);
    vbox<<<dim3(BB * (HH / HSEG) * 24), 256, 0, stream>>>(Hws, outp);
}